// Round 1
// 919.034 us; speedup vs baseline: 1.3444x; 1.3444x over previous
//
#include <hip/hip_runtime.h>
#include <hip/hip_bf16.h>

using bf16 = __hip_bfloat16;
typedef __attribute__((ext_vector_type(8))) short short8;   // 8 bf16 = 4 VGPRs (MFMA A/B frag)
typedef __attribute__((ext_vector_type(4))) float f32x4;    // MFMA C/D frag

static __device__ __forceinline__ float b2f(bf16 x) { return __bfloat162float(x); }

static __device__ __forceinline__ unsigned int packbf2(float a, float b) {
    bf16 x = __float2bfloat16(a), y = __float2bfloat16(b);
    unsigned short ux = *(unsigned short*)&x, uy = *(unsigned short*)&y;
    return (unsigned int)ux | ((unsigned int)uy << 16);
}

// ---------------- dtype auto-detection (deterministic) -----------------------
// flags[0]=1 -> float inputs are fp32 (else bf16). flags[1]=1 -> edges int64.
__global__ void det_kernel(const unsigned short* __restrict__ xh,
                           const int* __restrict__ ei, int* __restrict__ flags) {
    __shared__ int s_exp, s_nz;
    if (threadIdx.x == 0) { s_exp = 0; s_nz = 0; }
    __syncthreads();
    if (threadIdx.x < 256) {
        unsigned short h = xh[threadIdx.x];
        int ef = (h >> 7) & 0xFF;
        if (ef < 100 || ef > 140) atomicAdd(&s_exp, 1);
    }
    for (int i = 1 + 2 * threadIdx.x; i < 4096; i += 2 * blockDim.x)
        if (ei[i] != 0) atomicAdd(&s_nz, 1);
    __syncthreads();
    if (threadIdx.x == 0) {
        flags[0] = (s_exp > 16) ? 1 : 0;
        flags[1] = (s_nz == 0) ? 1 : 0;
    }
}

// ---------------- canonicalizers --------------------------------------------
__global__ void canon_w(const void* __restrict__ src, const int* __restrict__ flags,
                        float* __restrict__ dst, int n) {
    int i = blockIdx.x * blockDim.x + threadIdx.x;
    if (i >= n) return;
    dst[i] = flags[0] ? ((const float*)src)[i] : b2f(((const bf16*)src)[i]);
}

__global__ void canon_x(const void* __restrict__ src, const int* __restrict__ flags,
                        bf16* __restrict__ dst, int n) {
    int i = blockIdx.x * blockDim.x + threadIdx.x;
    if (i >= n) return;
    dst[i] = flags[0] ? __float2bfloat16(((const float*)src)[i]) : ((const bf16*)src)[i];
}

__global__ void canon_edges(const int* __restrict__ ei, const int* __restrict__ flags,
                            int* __restrict__ srcd, int* __restrict__ dstd, int E) {
    int e = blockIdx.x * blockDim.x + threadIdx.x;
    if (e >= E) return;
    if (flags[1]) { srcd[e] = ei[2 * e]; dstd[e] = ei[2 * E + 2 * e]; }
    else          { srcd[e] = ei[e];     dstd[e] = ei[E + e]; }
}

// Split fp32 weights W[K,F] into transposed bf16 hi/lo pair Wt[F,K].
// W == hi + lo to ~16 mantissa bits, so MFMA(A,hi)+MFMA(A,lo) with fp32
// accumulate reproduces the fp32-weight GEMM (A is bf16-exact already).
__global__ void prep_wt(const void* __restrict__ src, const int* __restrict__ flags,
                        bf16* __restrict__ Wth, bf16* __restrict__ Wtl, int K, int F) {
    int j = blockIdx.x * blockDim.x + threadIdx.x;   // j = f*K + k (coalesced writes)
    if (j >= K * F) return;
    int f = j / K, k = j - f * K;
    float v = flags[0] ? ((const float*)src)[(size_t)k * F + f]
                       : b2f(((const bf16*)src)[(size_t)k * F + f]);
    bf16 hi = __float2bfloat16(v);
    float lo = v - b2f(hi);
    Wth[j] = hi;
    Wtl[j] = __float2bfloat16(lo);
}

// ---------------- CSR build -------------------------------------------------
__global__ void hist_kernel(const int* __restrict__ dstv, int* __restrict__ counts, int E) {
    int e = blockIdx.x * blockDim.x + threadIdx.x;
    if (e < E) atomicAdd(&counts[dstv[e]], 1);
}

// single-block exclusive scan over counts[0..N) -> rowPtr, cursor; also dinv.
__global__ void scan_kernel(const int* __restrict__ counts, int* __restrict__ rowPtr,
                            int* __restrict__ cursor, float* __restrict__ dinv, int N) {
    __shared__ int sums[1024];
    const int tid = threadIdx.x;
    const int chunk = (N + 1023) / 1024;
    int beg = tid * chunk, end = beg + chunk;
    if (beg > N) beg = N;
    if (end > N) end = N;
    int s = 0;
    for (int i = beg; i < end; ++i) s += counts[i];
    sums[tid] = s;
    __syncthreads();
    for (int off = 1; off < 1024; off <<= 1) {
        int v = (tid >= off) ? sums[tid - off] : 0;
        __syncthreads();
        sums[tid] += v;
        __syncthreads();
    }
    int run = (tid > 0) ? sums[tid - 1] : 0;
    for (int i = beg; i < end; ++i) {
        rowPtr[i] = run; cursor[i] = run;
        dinv[i] = rsqrtf((float)counts[i] + 1.0f);
        run += counts[i];
    }
    if (tid == 1023) rowPtr[N] = run;
}

__global__ void scatter_kernel(const int* __restrict__ srcv, const int* __restrict__ dstv,
                               int* __restrict__ cursor, int* __restrict__ sortedSrc, int E) {
    int e = blockIdx.x * blockDim.x + threadIdx.x;
    if (e >= E) return;
    int p = atomicAdd(&cursor[dstv[e]], 1);
    sortedSrc[p] = srcv[e];
}

// ---------------- MFMA GEMM -------------------------------------------------
// C[N,F] = A[N,K](bf16) @ (Wth+Wtl)[K,F], epilogue: *dinv[row] (opt) + bias[col] (opt).
// Block: 256 thr = 4 waves; tile 64 rows x 64 cols; K chunked by 64.
// LDS (24 KB/chunk): A 64x64 bf16 | Wth 64x64 | Wtl 64x64, each row XOR-swizzled
// at 16B granularity (granule c stored at slot c^(row&7)) so ds_read_b128 of a
// column-slice across 16 rows is bank-conflict-free (G4). global_load_lds writes
// linearly, so the global source address carries the inverse (== same) XOR (rule 21).
template <int K>
__global__ __launch_bounds__(256)
void mfma_gemm(const bf16* __restrict__ A,
               const bf16* __restrict__ Wth, const bf16* __restrict__ Wtl,
               const float* __restrict__ bias, const float* __restrict__ dinv,
               void* __restrict__ out, const int* __restrict__ flags,
               int outmode, int F, int N) {
    __shared__ uint4 lds4[1536];               // 24 KB = 1536 x 16B granules
    char* lds = (char*)lds4;
    const int tid = threadIdx.x;
    const int w = tid >> 6, lane = tid & 63;
    const int rowBase = blockIdx.y * 64;       // blockIdx.x = col block -> A stays L2-hot
    const int colBase = blockIdx.x * 64;

    f32x4 zero = {0.f, 0.f, 0.f, 0.f};
    f32x4 acc[4];
#pragma unroll
    for (int n = 0; n < 4; ++n) acc[n] = zero;

    const int arow = (w << 4) + (lane & 15);   // wave w owns tile rows 16w..16w+15
    const int aswz = arow & 7;
    const int colL = lane & 15;

    for (int kc = 0; kc < K; kc += 64) {
        // ---- stage A/Wth/Wtl chunk: 6 x global_load_lds_dwordx4 per thread-slot
#pragma unroll
        for (int i = 0; i < 6; ++i) {
            const int g = i * 256 + tid;                        // LDS granule index
            char* dst = lds + ((i * 256 + (w << 6)) << 4);      // wave-uniform base
            const bf16* src;
            if (g < 512) {                                      // A tile
                int r = g >> 3, c = g & 7;
                int gr = rowBase + r; if (gr >= N) gr = N - 1;  // clamp tail rows
                src = A + (size_t)gr * K + kc + ((c ^ (r & 7)) << 3);
            } else if (g < 1024) {                              // Wth tile
                int h = g - 512; int cl = h >> 3, c = h & 7;
                src = Wth + (size_t)(colBase + cl) * K + kc + ((c ^ (cl & 7)) << 3);
            } else {                                            // Wtl tile
                int h = g - 1024; int cl = h >> 3, c = h & 7;
                src = Wtl + (size_t)(colBase + cl) * K + kc + ((c ^ (cl & 7)) << 3);
            }
            __builtin_amdgcn_global_load_lds(
                (const __attribute__((address_space(1))) void*)src,
                (__attribute__((address_space(3))) void*)dst, 16, 0, 0);
        }
        __syncthreads();   // drains vmcnt before barrier (compiler-enforced)

        const char* aB = lds;
        const char* hB = lds + 8192;
        const char* lB = lds + 16384;
#pragma unroll
        for (int ks = 0; ks < 2; ++ks) {                        // 2 k-steps of 32
            const int c = (ks << 2) + (lane >> 4);              // 16B granule along K
            short8 a = *(const short8*)(aB + (((arow << 3) + (c ^ aswz)) << 4));
#pragma unroll
            for (int n = 0; n < 4; ++n) {
                const int col = (n << 4) + colL;
                const int s = ((col << 3) + (c ^ (col & 7))) << 4;
                short8 bh = *(const short8*)(hB + s);
                short8 bl = *(const short8*)(lB + s);
                acc[n] = __builtin_amdgcn_mfma_f32_16x16x32_bf16(a, bh, acc[n], 0, 0, 0);
                acc[n] = __builtin_amdgcn_mfma_f32_16x16x32_bf16(a, bl, acc[n], 0, 0, 0);
            }
        }
        __syncthreads();
    }

    // ---- epilogue: C/D layout col = lane&15, row = (lane>>4)*4 + reg (m89/m91)
    const int m32 = outmode ? flags[0] : 0;
    const int r0 = rowBase + (w << 4) + ((lane >> 4) << 2);
#pragma unroll
    for (int n = 0; n < 4; ++n) {
        const int col = colBase + (n << 4) + colL;
        const float bv = bias ? bias[col] : 0.0f;
#pragma unroll
        for (int r = 0; r < 4; ++r) {
            const int row = r0 + r;
            if (row < N) {
                float v = acc[n][r];
                if (dinv) v *= dinv[row];
                v += bv;
                size_t o = (size_t)row * F + col;
                if (m32) ((float*)out)[o] = v;
                else     ((bf16*)out)[o] = __float2bfloat16(v);
            }
        }
    }
}

// ---------------- fused gather-aggregate + self-loop + bias + act -----------
template <int F>
static __device__ __forceinline__ void acc_row(const bf16* __restrict__ Hs, int row, int lane,
                                               float* acc) {
    if constexpr (F == 64) {
        unsigned short u = ((const unsigned short*)Hs)[(size_t)row * 64 + lane];
        union { unsigned int i; float f; } c; c.i = (unsigned int)u << 16;
        acc[0] += c.f;
    } else if constexpr (F == 128) {
        unsigned int u = ((const unsigned int*)(Hs + (size_t)row * 128))[lane];
        union { unsigned int i; float f; } lo, hi;
        lo.i = u << 16; hi.i = u & 0xffff0000u;
        acc[0] += lo.f; acc[1] += hi.f;
    } else {
        uint2 u = ((const uint2*)(Hs + (size_t)row * 256))[lane];
        union { unsigned int i; float f; } a, b, c, d;
        a.i = u.x << 16; b.i = u.x & 0xffff0000u;
        c.i = u.y << 16; d.i = u.y & 0xffff0000u;
        acc[0] += a.f; acc[1] += b.f; acc[2] += c.f; acc[3] += d.f;
    }
}

template <int F>
__global__ void gather_kernel(const bf16* __restrict__ Hs, const int* __restrict__ rowPtr,
                              const int* __restrict__ sortedSrc, const float* __restrict__ dinv,
                              const float* __restrict__ bias, bf16* __restrict__ out,
                              int relu, int N) {
    constexpr int WPL = F / 64;                    // bf16 per lane
    int node = blockIdx.x * (blockDim.x >> 6) + (threadIdx.x >> 6);
    int lane = threadIdx.x & 63;
    if (node >= N) return;
    float acc[WPL];
#pragma unroll
    for (int w = 0; w < WPL; ++w) acc[w] = 0.0f;
    acc_row<F>(Hs, node, lane, acc);               // self-loop term
    const int beg = rowPtr[node], end = rowPtr[node + 1];
    for (int b = beg; b < end; b += 64) {
        int n = end - b; if (n > 64) n = 64;
        int myS = (lane < n) ? sortedSrc[b + lane] : 0;
        int j = 0;
        for (; j + 1 < n; j += 2) {               // 2 gathers in flight
            int s0 = __shfl(myS, j), s1 = __shfl(myS, j + 1);
            acc_row<F>(Hs, s0, lane, acc);
            acc_row<F>(Hs, s1, lane, acc);
        }
        if (j < n) acc_row<F>(Hs, __shfl(myS, j), lane, acc);
    }
    const float di = dinv[node];
    if constexpr (F == 64) {
        float v = acc[0] * di + bias[lane];
        if (relu) v = fmaxf(v, 0.0f);
        bf16 o = __float2bfloat16(v);
        ((unsigned short*)out)[(size_t)node * 64 + lane] = *(unsigned short*)&o;
    } else if constexpr (F == 128) {
        float v0 = acc[0] * di + bias[2 * lane];
        float v1 = acc[1] * di + bias[2 * lane + 1];
        if (relu) { v0 = fmaxf(v0, 0.0f); v1 = fmaxf(v1, 0.0f); }
        ((unsigned int*)(out + (size_t)node * 128))[lane] = packbf2(v0, v1);
    } else {
        float v0 = acc[0] * di + bias[4 * lane];
        float v1 = acc[1] * di + bias[4 * lane + 1];
        float v2 = acc[2] * di + bias[4 * lane + 2];
        float v3 = acc[3] * di + bias[4 * lane + 3];
        if (relu) { v0 = fmaxf(v0, 0.0f); v1 = fmaxf(v1, 0.0f);
                    v2 = fmaxf(v2, 0.0f); v3 = fmaxf(v3, 0.0f); }
        uint2 p; p.x = packbf2(v0, v1); p.y = packbf2(v2, v3);
        ((uint2*)(out + (size_t)node * 256))[lane] = p;
    }
}

// ---------------- link predictor --------------------------------------------
__global__ void link_kernel(const bf16* __restrict__ Z, const int* __restrict__ srcv,
                            const int* __restrict__ dstv, const float* __restrict__ lw,
                            const float* __restrict__ lb, void* __restrict__ out,
                            const int* __restrict__ flags, size_t outOff, int E) {
    size_t gtid = blockIdx.x * (size_t)blockDim.x + threadIdx.x;
    int e = (int)(gtid >> 6);
    int lane = (int)(gtid & 63);
    if (e >= E) return;
    int s = srcv[e], d = dstv[e];
    float v = b2f(Z[(size_t)s * 64 + lane]) * lw[lane]
            + b2f(Z[(size_t)d * 64 + lane]) * lw[64 + lane];
#pragma unroll
    for (int off = 32; off > 0; off >>= 1) v += __shfl_down(v, off);
    if (lane == 0) {
        float sv = 1.0f / (1.0f + expf(-(v + lb[0])));
        if (flags[0]) ((float*)out)[outOff + e] = sv;
        else          ((bf16*)out)[outOff + e] = __float2bfloat16(sv);
    }
}

// ---------------- launch ----------------------------------------------------
extern "C" void kernel_launch(void* const* d_in, const int* in_sizes, int n_in,
                              void* d_out, int out_size, void* d_ws, size_t ws_size,
                              hipStream_t stream) {
    const int N = in_sizes[0] / 128;   // 50000
    const int E = in_sizes[1] / 2;     // 800000

    char* base = (char*)d_ws;
    size_t off = 0;
    auto alloc = [&](size_t bytes) { char* p = base + off; off = (off + bytes + 255) & ~(size_t)255; return p; };
    int*   flags  = (int*)  alloc(256);
    float* dinv   = (float*)alloc((size_t)N * 4);
    float* Wc     = (float*)alloc((size_t)210689 * 4);
    int*   counts = (int*)  alloc((size_t)N * 4);
    int*   rowPtr = (int*)  alloc(((size_t)N + 1) * 4);
    int*   cursor = (int*)  alloc((size_t)N * 4);
    int*   sortedSrc = (int*)alloc((size_t)E * 4);
    int*   srcd   = (int*)  alloc((size_t)E * 4);
    int*   dstd   = (int*)  alloc((size_t)E * 4);
    bf16*  Hs     = (bf16*) alloc((size_t)N * 256 * 2);  // scaled GEMM out H'
    bf16*  P0     = (bf16*) alloc((size_t)N * 256 * 2);  // layer output
    bf16*  z      = (bf16*) alloc((size_t)N * 64 * 2);
    bf16*  Wth    = (bf16*) alloc((size_t)208896 * 2);   // transposed bf16-hi weights
    bf16*  Wtl    = (bf16*) alloc((size_t)208896 * 2);   // transposed bf16-lo residuals

    // fp32 canon offsets (biases + link weights only now)
    const int W_EB1 = 16384, W_EB2 = 24704, W_EFB = 28864, W_DB1 = 45312,
              W_DB2 = 78336, W_DFB = 209536, W_LW = 210560, W_LB = 210688;
    // transposed hi/lo weight offsets (elements)
    const int T_EW1 = 0, T_EW2 = 16384, T_EFW = 24576, T_DW1 = 28672,
              T_DW2 = 45056, T_DFW = 77824;

    det_kernel<<<1, 256, 0, stream>>>((const unsigned short*)d_in[0], (const int*)d_in[1], flags);
    canon_edges<<<(E + 255) / 256, 256, 0, stream>>>((const int*)d_in[1], flags, srcd, dstd, E);

    // CSR + dinv
    hipMemsetAsync(counts, 0, (size_t)N * 4, stream);
    hist_kernel<<<(E + 255) / 256, 256, 0, stream>>>(dstd, counts, E);
    scan_kernel<<<1, 1024, 0, stream>>>(counts, rowPtr, cursor, dinv, N);
    scatter_kernel<<<(E + 255) / 256, 256, 0, stream>>>(srcd, dstd, cursor, sortedSrc, E);

    {   // biases / link weights -> canonical fp32
        const int idx[8]  = {3, 5, 7, 9, 11, 13, 14, 15};
        const int woff[8] = {W_EB1, W_EB2, W_EFB, W_DB1, W_DB2, W_DFB, W_LW, W_LB};
        for (int j = 0; j < 8; ++j) {
            int n = in_sizes[idx[j]];
            canon_w<<<(n + 255) / 256, 256, 0, stream>>>(d_in[idx[j]], flags, Wc + woff[j], n);
        }
    }
    {   // GEMM weights -> transposed bf16 hi/lo split
        const int idx[6]  = {2, 4, 6, 8, 10, 12};
        const int toff[6] = {T_EW1, T_EW2, T_EFW, T_DW1, T_DW2, T_DFW};
        const int kk[6]   = {128, 128, 64, 64, 256, 128};
        const int ff[6]   = {128, 64, 64, 256, 128, 1024};
        for (int j = 0; j < 6; ++j) {
            int n = kk[j] * ff[j];
            prep_wt<<<(n + 255) / 256, 256, 0, stream>>>(d_in[idx[j]], flags,
                                                         Wth + toff[j], Wtl + toff[j], kk[j], ff[j]);
        }
    }
    canon_x<<<(N * 128 + 255) / 256, 256, 0, stream>>>(d_in[0], flags, P0, N * 128);

    const int gRB = (N + 63) / 64;     // 782 row blocks (tail block: 16 valid rows)
    const int gG = (N + 3) / 4;        // gather: 4 nodes (waves) per 256-block

    // Encoder GCN1: 128 -> 128 (H' = dinv * X@W), ReLU applied in gather
    mfma_gemm<128><<<dim3(2, gRB), 256, 0, stream>>>(P0, Wth + T_EW1, Wtl + T_EW1,
                                                     nullptr, dinv, Hs, flags, 0, 128, N);
    gather_kernel<128><<<gG, 256, 0, stream>>>(Hs, rowPtr, sortedSrc, dinv, Wc + W_EB1, P0, 1, N);

    // Encoder GCN2: 128 -> 64
    mfma_gemm<128><<<dim3(1, gRB), 256, 0, stream>>>(P0, Wth + T_EW2, Wtl + T_EW2,
                                                     nullptr, dinv, Hs, flags, 0, 64, N);
    gather_kernel<64><<<gG, 256, 0, stream>>>(Hs, rowPtr, sortedSrc, dinv, Wc + W_EB2, P0, 0, N);

    // Latent fc: z = P0 @ efw + efb
    mfma_gemm<64><<<dim3(1, gRB), 256, 0, stream>>>(P0, Wth + T_EFW, Wtl + T_EFW,
                                                    Wc + W_EFB, nullptr, z, flags, 0, 64, N);

    // Decoder GCN1: 64 -> 256, ReLU in gather
    mfma_gemm<64><<<dim3(4, gRB), 256, 0, stream>>>(z, Wth + T_DW1, Wtl + T_DW1,
                                                    nullptr, dinv, Hs, flags, 0, 256, N);
    gather_kernel<256><<<gG, 256, 0, stream>>>(Hs, rowPtr, sortedSrc, dinv, Wc + W_DB1, P0, 1, N);

    // Decoder GCN2: 256 -> 128
    mfma_gemm<256><<<dim3(2, gRB), 256, 0, stream>>>(P0, Wth + T_DW2, Wtl + T_DW2,
                                                     nullptr, dinv, Hs, flags, 0, 128, N);
    gather_kernel<128><<<gG, 256, 0, stream>>>(Hs, rowPtr, sortedSrc, dinv, Wc + W_DB2, P0, 0, N);

    // x_hat = P0 @ dfw + dfb (128 -> 1024) into d_out, detected dtype
    mfma_gemm<128><<<dim3(16, gRB), 256, 0, stream>>>(P0, Wth + T_DFW, Wtl + T_DFW,
                                                      Wc + W_DFB, nullptr, d_out, flags, 1, 1024, N);

    // edge_probs
    link_kernel<<<((size_t)E * 64 + 255) / 256, 256, 0, stream>>>(z, srcd, dstd, Wc + W_LW, Wc + W_LB,
                                                                  d_out, flags, (size_t)N * 1024, E);
}

// Round 2
// 819.271 us; speedup vs baseline: 1.5081x; 1.1218x over previous
//
#include <hip/hip_runtime.h>
#include <hip/hip_bf16.h>

using bf16 = __hip_bfloat16;
typedef __attribute__((ext_vector_type(8))) short short8;   // 8 bf16 = 4 VGPRs (MFMA A/B frag)
typedef __attribute__((ext_vector_type(4))) float f32x4;    // MFMA C/D frag

static __device__ __forceinline__ float b2f(bf16 x) { return __bfloat162float(x); }

static __device__ __forceinline__ unsigned int packbf2(float a, float b) {
    bf16 x = __float2bfloat16(a), y = __float2bfloat16(b);
    unsigned short ux = *(unsigned short*)&x, uy = *(unsigned short*)&y;
    return (unsigned int)ux | ((unsigned int)uy << 16);
}

// ---------------- dtype auto-detection (deterministic) -----------------------
// flags[0]=1 -> float inputs are fp32 (else bf16). flags[1]=1 -> edges int64.
__global__ void det_kernel(const unsigned short* __restrict__ xh,
                           const int* __restrict__ ei, int* __restrict__ flags) {
    __shared__ int s_exp, s_nz;
    if (threadIdx.x == 0) { s_exp = 0; s_nz = 0; }
    __syncthreads();
    if (threadIdx.x < 256) {
        unsigned short h = xh[threadIdx.x];
        int ef = (h >> 7) & 0xFF;
        if (ef < 100 || ef > 140) atomicAdd(&s_exp, 1);
    }
    for (int i = 1 + 2 * threadIdx.x; i < 4096; i += 2 * blockDim.x)
        if (ei[i] != 0) atomicAdd(&s_nz, 1);
    __syncthreads();
    if (threadIdx.x == 0) {
        flags[0] = (s_exp > 16) ? 1 : 0;
        flags[1] = (s_nz == 0) ? 1 : 0;
    }
}

// ---------------- canonicalizers --------------------------------------------
__global__ void canon_w(const void* __restrict__ src, const int* __restrict__ flags,
                        float* __restrict__ dst, int n) {
    int i = blockIdx.x * blockDim.x + threadIdx.x;
    if (i >= n) return;
    dst[i] = flags[0] ? ((const float*)src)[i] : b2f(((const bf16*)src)[i]);
}

__global__ void canon_x(const void* __restrict__ src, const int* __restrict__ flags,
                        bf16* __restrict__ dst, int n) {
    int i = blockIdx.x * blockDim.x + threadIdx.x;
    if (i >= n) return;
    dst[i] = flags[0] ? __float2bfloat16(((const float*)src)[i]) : ((const bf16*)src)[i];
}

__global__ void canon_edges(const int* __restrict__ ei, const int* __restrict__ flags,
                            int* __restrict__ srcd, int* __restrict__ dstd, int E) {
    int e = blockIdx.x * blockDim.x + threadIdx.x;
    if (e >= E) return;
    if (flags[1]) { srcd[e] = ei[2 * e]; dstd[e] = ei[2 * E + 2 * e]; }
    else          { srcd[e] = ei[e];     dstd[e] = ei[E + e]; }
}

// Split fp32 weights W[K,F] into transposed bf16 hi/lo pair Wt[F,K].
// W == hi + lo to ~16 mantissa bits, so MFMA(A,hi)+MFMA(A,lo) with fp32
// accumulate reproduces the fp32-weight GEMM (A is bf16-exact already).
__global__ void prep_wt(const void* __restrict__ src, const int* __restrict__ flags,
                        bf16* __restrict__ Wth, bf16* __restrict__ Wtl, int K, int F) {
    int j = blockIdx.x * blockDim.x + threadIdx.x;   // j = f*K + k (coalesced writes)
    if (j >= K * F) return;
    int f = j / K, k = j - f * K;
    float v = flags[0] ? ((const float*)src)[(size_t)k * F + f]
                       : b2f(((const bf16*)src)[(size_t)k * F + f]);
    bf16 hi = __float2bfloat16(v);
    float lo = v - b2f(hi);
    Wth[j] = hi;
    Wtl[j] = __float2bfloat16(lo);
}

// ---------------- CSR build -------------------------------------------------
__global__ void hist_kernel(const int* __restrict__ dstv, int* __restrict__ counts, int E) {
    int e = blockIdx.x * blockDim.x + threadIdx.x;
    if (e < E) atomicAdd(&counts[dstv[e]], 1);
}

// single-block exclusive scan over counts[0..N) -> rowPtr, cursor; also dinv.
__global__ void scan_kernel(const int* __restrict__ counts, int* __restrict__ rowPtr,
                            int* __restrict__ cursor, float* __restrict__ dinv, int N) {
    __shared__ int sums[1024];
    const int tid = threadIdx.x;
    const int chunk = (N + 1023) / 1024;
    int beg = tid * chunk, end = beg + chunk;
    if (beg > N) beg = N;
    if (end > N) end = N;
    int s = 0;
    for (int i = beg; i < end; ++i) s += counts[i];
    sums[tid] = s;
    __syncthreads();
    for (int off = 1; off < 1024; off <<= 1) {
        int v = (tid >= off) ? sums[tid - off] : 0;
        __syncthreads();
        sums[tid] += v;
        __syncthreads();
    }
    int run = (tid > 0) ? sums[tid - 1] : 0;
    for (int i = beg; i < end; ++i) {
        rowPtr[i] = run; cursor[i] = run;
        dinv[i] = rsqrtf((float)counts[i] + 1.0f);
        run += counts[i];
    }
    if (tid == 1023) rowPtr[N] = run;
}

__global__ void scatter_kernel(const int* __restrict__ srcv, const int* __restrict__ dstv,
                               int* __restrict__ cursor, int* __restrict__ sortedSrc, int E) {
    int e = blockIdx.x * blockDim.x + threadIdx.x;
    if (e >= E) return;
    int p = atomicAdd(&cursor[dstv[e]], 1);
    sortedSrc[p] = srcv[e];
}

// ---------------- MFMA GEMM -------------------------------------------------
// C[N,F] = A[N,K](bf16) @ (Wth+Wtl)[K,F], epilogue: *dinv[row] (opt) + bias[col] (opt).
// Block: 256 thr = 4 waves; tile 64 rows x 64 cols; K chunked by 64.
// LDS (24 KB/chunk): A 64x64 bf16 | Wth 64x64 | Wtl 64x64, each row XOR-swizzled
// at 16B granularity (granule c stored at slot c^(row&7)) so ds_read_b128 of a
// column-slice across 16 rows is bank-conflict-free (G4). global_load_lds writes
// linearly, so the global source address carries the inverse (== same) XOR (rule 21).
template <int K>
__global__ __launch_bounds__(256)
void mfma_gemm(const bf16* __restrict__ A,
               const bf16* __restrict__ Wth, const bf16* __restrict__ Wtl,
               const float* __restrict__ bias, const float* __restrict__ dinv,
               void* __restrict__ out, const int* __restrict__ flags,
               int outmode, int F, int N) {
    __shared__ uint4 lds4[1536];               // 24 KB = 1536 x 16B granules
    char* lds = (char*)lds4;
    const int tid = threadIdx.x;
    const int w = tid >> 6, lane = tid & 63;
    const int rowBase = blockIdx.y * 64;       // blockIdx.x = col block -> A stays L2-hot
    const int colBase = blockIdx.x * 64;

    f32x4 zero = {0.f, 0.f, 0.f, 0.f};
    f32x4 acc[4];
#pragma unroll
    for (int n = 0; n < 4; ++n) acc[n] = zero;

    const int arow = (w << 4) + (lane & 15);   // wave w owns tile rows 16w..16w+15
    const int aswz = arow & 7;
    const int colL = lane & 15;

    for (int kc = 0; kc < K; kc += 64) {
        // ---- stage A/Wth/Wtl chunk: 6 x global_load_lds_dwordx4 per thread-slot
#pragma unroll
        for (int i = 0; i < 6; ++i) {
            const int g = i * 256 + tid;                        // LDS granule index
            char* dst = lds + ((i * 256 + (w << 6)) << 4);      // wave-uniform base
            const bf16* src;
            if (g < 512) {                                      // A tile
                int r = g >> 3, c = g & 7;
                int gr = rowBase + r; if (gr >= N) gr = N - 1;  // clamp tail rows
                src = A + (size_t)gr * K + kc + ((c ^ (r & 7)) << 3);
            } else if (g < 1024) {                              // Wth tile
                int h = g - 512; int cl = h >> 3, c = h & 7;
                src = Wth + (size_t)(colBase + cl) * K + kc + ((c ^ (cl & 7)) << 3);
            } else {                                            // Wtl tile
                int h = g - 1024; int cl = h >> 3, c = h & 7;
                src = Wtl + (size_t)(colBase + cl) * K + kc + ((c ^ (cl & 7)) << 3);
            }
            __builtin_amdgcn_global_load_lds(
                (const __attribute__((address_space(1))) void*)src,
                (__attribute__((address_space(3))) void*)dst, 16, 0, 0);
        }
        __syncthreads();   // drains vmcnt before barrier (compiler-enforced)

        const char* aB = lds;
        const char* hB = lds + 8192;
        const char* lB = lds + 16384;
#pragma unroll
        for (int ks = 0; ks < 2; ++ks) {                        // 2 k-steps of 32
            const int c = (ks << 2) + (lane >> 4);              // 16B granule along K
            short8 a = *(const short8*)(aB + (((arow << 3) + (c ^ aswz)) << 4));
#pragma unroll
            for (int n = 0; n < 4; ++n) {
                const int col = (n << 4) + colL;
                const int s = ((col << 3) + (c ^ (col & 7))) << 4;
                short8 bh = *(const short8*)(hB + s);
                short8 bl = *(const short8*)(lB + s);
                acc[n] = __builtin_amdgcn_mfma_f32_16x16x32_bf16(a, bh, acc[n], 0, 0, 0);
                acc[n] = __builtin_amdgcn_mfma_f32_16x16x32_bf16(a, bl, acc[n], 0, 0, 0);
            }
        }
        __syncthreads();
    }

    // ---- epilogue: C/D layout col = lane&15, row = (lane>>4)*4 + reg (m89/m91)
    const int m32 = outmode ? flags[0] : 0;
    const int r0 = rowBase + (w << 4) + ((lane >> 4) << 2);
#pragma unroll
    for (int n = 0; n < 4; ++n) {
        const int col = colBase + (n << 4) + colL;
        const float bv = bias ? bias[col] : 0.0f;
#pragma unroll
        for (int r = 0; r < 4; ++r) {
            const int row = r0 + r;
            if (row < N) {
                float v = acc[n][r];
                if (dinv) v *= dinv[row];
                v += bv;
                size_t o = (size_t)row * F + col;
                if (m32) ((float*)out)[o] = v;
                else     ((bf16*)out)[o] = __float2bfloat16(v);
            }
        }
    }
}

// ---------------- fused gather-aggregate + self-loop + bias + act -----------
template <int F>
static __device__ __forceinline__ void acc_row(const bf16* __restrict__ Hs, int row, int lane,
                                               float* acc) {
    if constexpr (F == 64) {
        unsigned short u = ((const unsigned short*)Hs)[(size_t)row * 64 + lane];
        union { unsigned int i; float f; } c; c.i = (unsigned int)u << 16;
        acc[0] += c.f;
    } else if constexpr (F == 128) {
        unsigned int u = ((const unsigned int*)(Hs + (size_t)row * 128))[lane];
        union { unsigned int i; float f; } lo, hi;
        lo.i = u << 16; hi.i = u & 0xffff0000u;
        acc[0] += lo.f; acc[1] += hi.f;
    } else {
        uint2 u = ((const uint2*)(Hs + (size_t)row * 256))[lane];
        union { unsigned int i; float f; } a, b, c, d;
        a.i = u.x << 16; b.i = u.x & 0xffff0000u;
        c.i = u.y << 16; d.i = u.y & 0xffff0000u;
        acc[0] += a.f; acc[1] += b.f; acc[2] += c.f; acc[3] += d.f;
    }
}

template <int F>
__global__ void gather_kernel(const bf16* __restrict__ Hs, const int* __restrict__ rowPtr,
                              const int* __restrict__ sortedSrc, const float* __restrict__ dinv,
                              const float* __restrict__ bias, bf16* __restrict__ out,
                              int relu, int N) {
    constexpr int WPL = F / 64;                    // bf16 per lane
    int node = blockIdx.x * (blockDim.x >> 6) + (threadIdx.x >> 6);
    int lane = threadIdx.x & 63;
    if (node >= N) return;
    float acc[WPL];
#pragma unroll
    for (int w = 0; w < WPL; ++w) acc[w] = 0.0f;
    acc_row<F>(Hs, node, lane, acc);               // self-loop term
    const int beg = rowPtr[node], end = rowPtr[node + 1];
    for (int b = beg; b < end; b += 64) {
        int n = end - b; if (n > 64) n = 64;
        int myS = (lane < n) ? sortedSrc[b + lane] : 0;
        int j = 0;
        for (; j + 1 < n; j += 2) {               // 2 gathers in flight
            int s0 = __shfl(myS, j), s1 = __shfl(myS, j + 1);
            acc_row<F>(Hs, s0, lane, acc);
            acc_row<F>(Hs, s1, lane, acc);
        }
        if (j < n) acc_row<F>(Hs, __shfl(myS, j), lane, acc);
    }
    const float di = dinv[node];
    if constexpr (F == 64) {
        float v = acc[0] * di + bias[lane];
        if (relu) v = fmaxf(v, 0.0f);
        bf16 o = __float2bfloat16(v);
        ((unsigned short*)out)[(size_t)node * 64 + lane] = *(unsigned short*)&o;
    } else if constexpr (F == 128) {
        float v0 = acc[0] * di + bias[2 * lane];
        float v1 = acc[1] * di + bias[2 * lane + 1];
        if (relu) { v0 = fmaxf(v0, 0.0f); v1 = fmaxf(v1, 0.0f); }
        ((unsigned int*)(out + (size_t)node * 128))[lane] = packbf2(v0, v1);
    } else {
        float v0 = acc[0] * di + bias[4 * lane];
        float v1 = acc[1] * di + bias[4 * lane + 1];
        float v2 = acc[2] * di + bias[4 * lane + 2];
        float v3 = acc[3] * di + bias[4 * lane + 3];
        if (relu) { v0 = fmaxf(v0, 0.0f); v1 = fmaxf(v1, 0.0f);
                    v2 = fmaxf(v2, 0.0f); v3 = fmaxf(v3, 0.0f); }
        uint2 p; p.x = packbf2(v0, v1); p.y = packbf2(v2, v3);
        ((uint2*)(out + (size_t)node * 256))[lane] = p;
    }
}

// ---------------- link predictor --------------------------------------------
// Linear-before-sigmoid => per-node partials: a[n]=z[n]@lw[:64], b[n]=z[n]@lw[64:].
// edge_prob = sigmoid(a[src] + b[dst] + lb). ab[] is 400 KB -> L2-resident.
__global__ void link_pre(const bf16* __restrict__ Z, const float* __restrict__ lw,
                         float* __restrict__ ab, int N) {
    int node = blockIdx.x * (blockDim.x >> 6) + (threadIdx.x >> 6);
    int lane = threadIdx.x & 63;
    if (node >= N) return;
    float zv = b2f(Z[(size_t)node * 64 + lane]);
    float va = zv * lw[lane];
    float vb = zv * lw[64 + lane];
#pragma unroll
    for (int off = 32; off > 0; off >>= 1) {
        va += __shfl_down(va, off);
        vb += __shfl_down(vb, off);
    }
    if (lane == 0) { ab[2 * node] = va; ab[2 * node + 1] = vb; }
}

__global__ void link_edge(const float* __restrict__ ab, const int* __restrict__ srcv,
                          const int* __restrict__ dstv, const float* __restrict__ lb,
                          void* __restrict__ out, const int* __restrict__ flags,
                          size_t outOff, int E) {
    int e = blockIdx.x * blockDim.x + threadIdx.x;
    if (e >= E) return;
    float v = ab[2 * srcv[e]] + ab[2 * dstv[e] + 1] + lb[0];
    float sv = 1.0f / (1.0f + expf(-v));
    if (flags[0]) ((float*)out)[outOff + e] = sv;
    else          ((bf16*)out)[outOff + e] = __float2bfloat16(sv);
}

// ---------------- launch ----------------------------------------------------
extern "C" void kernel_launch(void* const* d_in, const int* in_sizes, int n_in,
                              void* d_out, int out_size, void* d_ws, size_t ws_size,
                              hipStream_t stream) {
    const int N = in_sizes[0] / 128;   // 50000
    const int E = in_sizes[1] / 2;     // 800000

    char* base = (char*)d_ws;
    size_t off = 0;
    auto alloc = [&](size_t bytes) { char* p = base + off; off = (off + bytes + 255) & ~(size_t)255; return p; };
    int*   flags  = (int*)  alloc(256);
    float* dinv   = (float*)alloc((size_t)N * 4);
    float* Wc     = (float*)alloc((size_t)210689 * 4);
    int*   counts = (int*)  alloc((size_t)N * 4);
    int*   rowPtr = (int*)  alloc(((size_t)N + 1) * 4);
    int*   cursor = (int*)  alloc((size_t)N * 4);
    int*   sortedSrc = (int*)alloc((size_t)E * 4);
    int*   srcd   = (int*)  alloc((size_t)E * 4);
    int*   dstd   = (int*)  alloc((size_t)E * 4);
    bf16*  Hs     = (bf16*) alloc((size_t)N * 256 * 2);  // scaled GEMM out H'
    bf16*  P0     = (bf16*) alloc((size_t)N * 256 * 2);  // layer output
    bf16*  z      = (bf16*) alloc((size_t)N * 64 * 2);
    bf16*  Wth    = (bf16*) alloc((size_t)208896 * 2);   // transposed bf16-hi weights
    bf16*  Wtl    = (bf16*) alloc((size_t)208896 * 2);   // transposed bf16-lo residuals
    float* ab     = (float*)alloc((size_t)N * 2 * 4);    // per-node link partials

    // fp32 canon offsets (biases + link weights only now)
    const int W_EB1 = 16384, W_EB2 = 24704, W_EFB = 28864, W_DB1 = 45312,
              W_DB2 = 78336, W_DFB = 209536, W_LW = 210560, W_LB = 210688;
    // transposed hi/lo weight offsets (elements)
    const int T_EW1 = 0, T_EW2 = 16384, T_EFW = 24576, T_DW1 = 28672,
              T_DW2 = 45056, T_DFW = 77824;

    det_kernel<<<1, 256, 0, stream>>>((const unsigned short*)d_in[0], (const int*)d_in[1], flags);
    canon_edges<<<(E + 255) / 256, 256, 0, stream>>>((const int*)d_in[1], flags, srcd, dstd, E);

    // CSR + dinv
    hipMemsetAsync(counts, 0, (size_t)N * 4, stream);
    hist_kernel<<<(E + 255) / 256, 256, 0, stream>>>(dstd, counts, E);
    scan_kernel<<<1, 1024, 0, stream>>>(counts, rowPtr, cursor, dinv, N);
    scatter_kernel<<<(E + 255) / 256, 256, 0, stream>>>(srcd, dstd, cursor, sortedSrc, E);

    {   // biases / link weights -> canonical fp32
        const int idx[8]  = {3, 5, 7, 9, 11, 13, 14, 15};
        const int woff[8] = {W_EB1, W_EB2, W_EFB, W_DB1, W_DB2, W_DFB, W_LW, W_LB};
        for (int j = 0; j < 8; ++j) {
            int n = in_sizes[idx[j]];
            canon_w<<<(n + 255) / 256, 256, 0, stream>>>(d_in[idx[j]], flags, Wc + woff[j], n);
        }
    }
    {   // GEMM weights -> transposed bf16 hi/lo split
        const int idx[6]  = {2, 4, 6, 8, 10, 12};
        const int toff[6] = {T_EW1, T_EW2, T_EFW, T_DW1, T_DW2, T_DFW};
        const int kk[6]   = {128, 128, 64, 64, 256, 128};
        const int ff[6]   = {128, 64, 64, 256, 128, 1024};
        for (int j = 0; j < 6; ++j) {
            int n = kk[j] * ff[j];
            prep_wt<<<(n + 255) / 256, 256, 0, stream>>>(d_in[idx[j]], flags,
                                                         Wth + toff[j], Wtl + toff[j], kk[j], ff[j]);
        }
    }
    canon_x<<<(N * 128 + 255) / 256, 256, 0, stream>>>(d_in[0], flags, P0, N * 128);

    const int gRB = (N + 63) / 64;     // 782 row blocks (tail block: 16 valid rows)
    const int gG = (N + 3) / 4;        // gather: 4 nodes (waves) per 256-block

    // Encoder GCN1: 128 -> 128 (H' = dinv * X@W), ReLU applied in gather
    mfma_gemm<128><<<dim3(2, gRB), 256, 0, stream>>>(P0, Wth + T_EW1, Wtl + T_EW1,
                                                     nullptr, dinv, Hs, flags, 0, 128, N);
    gather_kernel<128><<<gG, 256, 0, stream>>>(Hs, rowPtr, sortedSrc, dinv, Wc + W_EB1, P0, 1, N);

    // Encoder GCN2: 128 -> 64
    mfma_gemm<128><<<dim3(1, gRB), 256, 0, stream>>>(P0, Wth + T_EW2, Wtl + T_EW2,
                                                     nullptr, dinv, Hs, flags, 0, 64, N);
    gather_kernel<64><<<gG, 256, 0, stream>>>(Hs, rowPtr, sortedSrc, dinv, Wc + W_EB2, P0, 0, N);

    // Latent fc: z = P0 @ efw + efb
    mfma_gemm<64><<<dim3(1, gRB), 256, 0, stream>>>(P0, Wth + T_EFW, Wtl + T_EFW,
                                                    Wc + W_EFB, nullptr, z, flags, 0, 64, N);

    // link partials can go as soon as z exists (overlap with decoder GEMMs)
    link_pre<<<gG, 256, 0, stream>>>(z, Wc + W_LW, ab, N);

    // Decoder GCN1: 64 -> 256, ReLU in gather
    mfma_gemm<64><<<dim3(4, gRB), 256, 0, stream>>>(z, Wth + T_DW1, Wtl + T_DW1,
                                                    nullptr, dinv, Hs, flags, 0, 256, N);
    gather_kernel<256><<<gG, 256, 0, stream>>>(Hs, rowPtr, sortedSrc, dinv, Wc + W_DB1, P0, 1, N);

    // Decoder GCN2: 256 -> 128
    mfma_gemm<256><<<dim3(2, gRB), 256, 0, stream>>>(P0, Wth + T_DW2, Wtl + T_DW2,
                                                     nullptr, dinv, Hs, flags, 0, 128, N);
    gather_kernel<128><<<gG, 256, 0, stream>>>(Hs, rowPtr, sortedSrc, dinv, Wc + W_DB2, P0, 0, N);

    // x_hat = P0 @ dfw + dfb (128 -> 1024) into d_out, detected dtype
    mfma_gemm<128><<<dim3(16, gRB), 256, 0, stream>>>(P0, Wth + T_DFW, Wtl + T_DFW,
                                                      Wc + W_DFB, nullptr, d_out, flags, 1, 1024, N);

    // edge_probs: 1 thread/edge against L2-resident ab[]
    link_edge<<<(E + 255) / 256, 256, 0, stream>>>(ab, srcd, dstd, Wc + W_LB,
                                                   d_out, flags, (size_t)N * 1024, E);
}

// Round 3
// 689.806 us; speedup vs baseline: 1.7911x; 1.1877x over previous
//
#include <hip/hip_runtime.h>
#include <hip/hip_bf16.h>

using bf16 = __hip_bfloat16;
typedef __attribute__((ext_vector_type(8))) short short8;   // 8 bf16 = 4 VGPRs (MFMA A/B frag)
typedef __attribute__((ext_vector_type(4))) float f32x4;    // MFMA C/D frag

static __device__ __forceinline__ float b2f(bf16 x) { return __bfloat162float(x); }

static __device__ __forceinline__ unsigned int packbf2(float a, float b) {
    bf16 x = __float2bfloat16(a), y = __float2bfloat16(b);
    unsigned short ux = *(unsigned short*)&x, uy = *(unsigned short*)&y;
    return (unsigned int)ux | ((unsigned int)uy << 16);
}

// ---------------- dtype auto-detection (deterministic) -----------------------
// flags[0]=1 -> float inputs are fp32 (else bf16). flags[1]=1 -> edges int64.
__global__ void det_kernel(const unsigned short* __restrict__ xh,
                           const int* __restrict__ ei, int* __restrict__ flags) {
    __shared__ int s_exp, s_nz;
    if (threadIdx.x == 0) { s_exp = 0; s_nz = 0; }
    __syncthreads();
    if (threadIdx.x < 256) {
        unsigned short h = xh[threadIdx.x];
        int ef = (h >> 7) & 0xFF;
        if (ef < 100 || ef > 140) atomicAdd(&s_exp, 1);
    }
    for (int i = 1 + 2 * threadIdx.x; i < 4096; i += 2 * blockDim.x)
        if (ei[i] != 0) atomicAdd(&s_nz, 1);
    __syncthreads();
    if (threadIdx.x == 0) {
        flags[0] = (s_exp > 16) ? 1 : 0;
        flags[1] = (s_nz == 0) ? 1 : 0;
    }
}

// ---------------- canonicalizers --------------------------------------------
__global__ void canon_w(const void* __restrict__ src, const int* __restrict__ flags,
                        float* __restrict__ dst, int n) {
    int i = blockIdx.x * blockDim.x + threadIdx.x;
    if (i >= n) return;
    dst[i] = flags[0] ? ((const float*)src)[i] : b2f(((const bf16*)src)[i]);
}

__global__ void canon_x(const void* __restrict__ src, const int* __restrict__ flags,
                        bf16* __restrict__ dst, int n) {
    int i = blockIdx.x * blockDim.x + threadIdx.x;
    if (i >= n) return;
    dst[i] = flags[0] ? __float2bfloat16(((const float*)src)[i]) : ((const bf16*)src)[i];
}

__global__ void canon_edges(const int* __restrict__ ei, const int* __restrict__ flags,
                            int* __restrict__ srcd, int* __restrict__ dstd, int E) {
    int e = blockIdx.x * blockDim.x + threadIdx.x;
    if (e >= E) return;
    if (flags[1]) { srcd[e] = ei[2 * e]; dstd[e] = ei[2 * E + 2 * e]; }
    else          { srcd[e] = ei[e];     dstd[e] = ei[E + e]; }
}

// Split fp32 weights W[K,F] into transposed bf16 hi/lo pair Wt[F,K].
// W == hi + lo to ~16 mantissa bits, so MFMA(A,hi)+MFMA(A,lo) with fp32
// accumulate reproduces the fp32-weight GEMM (A is bf16-exact already).
__global__ void prep_wt(const void* __restrict__ src, const int* __restrict__ flags,
                        bf16* __restrict__ Wth, bf16* __restrict__ Wtl, int K, int F) {
    int j = blockIdx.x * blockDim.x + threadIdx.x;   // j = f*K + k (coalesced writes)
    if (j >= K * F) return;
    int f = j / K, k = j - f * K;
    float v = flags[0] ? ((const float*)src)[(size_t)k * F + f]
                       : b2f(((const bf16*)src)[(size_t)k * F + f]);
    bf16 hi = __float2bfloat16(v);
    float lo = v - b2f(hi);
    Wth[j] = hi;
    Wtl[j] = __float2bfloat16(lo);
}

// ---------------- CSR build -------------------------------------------------
__global__ void hist_kernel(const int* __restrict__ dstv, int* __restrict__ counts, int E) {
    int e = blockIdx.x * blockDim.x + threadIdx.x;
    if (e < E) atomicAdd(&counts[dstv[e]], 1);
}

// Multi-block scan (196 blocks x 256 thr) replaces the 1-CU monolithic scan
// that was latency-bound on cross-XCD dirty lines (134 us, Occupancy 0.14%).
__global__ void scan_part1(const int* __restrict__ counts, int* __restrict__ blockSums, int N) {
    __shared__ int red[256];
    int i = blockIdx.x * 256 + threadIdx.x;
    red[threadIdx.x] = (i < N) ? counts[i] : 0;
    __syncthreads();
    for (int off = 128; off > 0; off >>= 1) {
        if (threadIdx.x < off) red[threadIdx.x] += red[threadIdx.x + off];
        __syncthreads();
    }
    if (threadIdx.x == 0) blockSums[blockIdx.x] = red[0];
}

// G <= 256 block sums -> exclusive block offsets; also writes rowPtr[N]=total.
__global__ void scan_part2(const int* __restrict__ blockSums, int* __restrict__ blockOff,
                           int* __restrict__ rowPtrN, int G) {
    __shared__ int s[256];
    int t = threadIdx.x;
    s[t] = (t < G) ? blockSums[t] : 0;
    __syncthreads();
    for (int off = 1; off < 256; off <<= 1) {
        int v = (t >= off) ? s[t - off] : 0;
        __syncthreads();
        s[t] += v;
        __syncthreads();
    }
    if (t < G) blockOff[t] = (t > 0) ? s[t - 1] : 0;
    if (t == 255) *rowPtrN = s[255];
}

__global__ void scan_part3(const int* __restrict__ counts, const int* __restrict__ blockOff,
                           int* __restrict__ rowPtr, int* __restrict__ cursor,
                           float* __restrict__ dinv, int N) {
    __shared__ int s[256];
    int t = threadIdx.x;
    int i = blockIdx.x * 256 + t;
    int c = (i < N) ? counts[i] : 0;
    s[t] = c;
    __syncthreads();
    for (int off = 1; off < 256; off <<= 1) {
        int v = (t >= off) ? s[t - off] : 0;
        __syncthreads();
        s[t] += v;
        __syncthreads();
    }
    if (i < N) {
        int o = blockOff[blockIdx.x] + s[t] - c;     // exclusive prefix
        rowPtr[i] = o;
        cursor[i] = o;
        dinv[i] = rsqrtf((float)c + 1.0f);
    }
}

__global__ void scatter_kernel(const int* __restrict__ srcv, const int* __restrict__ dstv,
                               int* __restrict__ cursor, int* __restrict__ sortedSrc, int E) {
    int e = blockIdx.x * blockDim.x + threadIdx.x;
    if (e >= E) return;
    int p = atomicAdd(&cursor[dstv[e]], 1);
    sortedSrc[p] = srcv[e];
}

// ---------------- MFMA GEMM -------------------------------------------------
// C[N,F] = A[N,K](bf16) @ (Wth+Wtl)[K,F], epilogue: *dinv[row] (opt) + bias[col] (opt).
// Block: 256 thr = 4 waves; tile 64 rows x 64 cols; K chunked by 64.
// LDS (24 KB/chunk): A 64x64 bf16 | Wth 64x64 | Wtl 64x64, each row XOR-swizzled
// at 16B granularity (granule c stored at slot c^(row&7)) so ds_read_b128 of a
// column-slice across 16 rows is bank-conflict-free (G4). global_load_lds writes
// linearly, so the global source address carries the inverse (== same) XOR (rule 21).
template <int K>
__global__ __launch_bounds__(256)
void mfma_gemm(const bf16* __restrict__ A,
               const bf16* __restrict__ Wth, const bf16* __restrict__ Wtl,
               const float* __restrict__ bias, const float* __restrict__ dinv,
               void* __restrict__ out, const int* __restrict__ flags,
               int outmode, int F, int N) {
    __shared__ uint4 lds4[1536];               // 24 KB = 1536 x 16B granules
    char* lds = (char*)lds4;
    const int tid = threadIdx.x;
    const int w = tid >> 6, lane = tid & 63;
    const int rowBase = blockIdx.y * 64;       // blockIdx.x = col block -> A stays L2-hot
    const int colBase = blockIdx.x * 64;

    f32x4 zero = {0.f, 0.f, 0.f, 0.f};
    f32x4 acc[4];
#pragma unroll
    for (int n = 0; n < 4; ++n) acc[n] = zero;

    const int arow = (w << 4) + (lane & 15);   // wave w owns tile rows 16w..16w+15
    const int aswz = arow & 7;
    const int colL = lane & 15;

    for (int kc = 0; kc < K; kc += 64) {
        // ---- stage A/Wth/Wtl chunk: 6 x global_load_lds_dwordx4 per thread-slot
#pragma unroll
        for (int i = 0; i < 6; ++i) {
            const int g = i * 256 + tid;                        // LDS granule index
            char* dst = lds + ((i * 256 + (w << 6)) << 4);      // wave-uniform base
            const bf16* src;
            if (g < 512) {                                      // A tile
                int r = g >> 3, c = g & 7;
                int gr = rowBase + r; if (gr >= N) gr = N - 1;  // clamp tail rows
                src = A + (size_t)gr * K + kc + ((c ^ (r & 7)) << 3);
            } else if (g < 1024) {                              // Wth tile
                int h = g - 512; int cl = h >> 3, c = h & 7;
                src = Wth + (size_t)(colBase + cl) * K + kc + ((c ^ (cl & 7)) << 3);
            } else {                                            // Wtl tile
                int h = g - 1024; int cl = h >> 3, c = h & 7;
                src = Wtl + (size_t)(colBase + cl) * K + kc + ((c ^ (cl & 7)) << 3);
            }
            __builtin_amdgcn_global_load_lds(
                (const __attribute__((address_space(1))) void*)src,
                (__attribute__((address_space(3))) void*)dst, 16, 0, 0);
        }
        __syncthreads();   // drains vmcnt before barrier (compiler-enforced)

        const char* aB = lds;
        const char* hB = lds + 8192;
        const char* lB = lds + 16384;
#pragma unroll
        for (int ks = 0; ks < 2; ++ks) {                        // 2 k-steps of 32
            const int c = (ks << 2) + (lane >> 4);              // 16B granule along K
            short8 a = *(const short8*)(aB + (((arow << 3) + (c ^ aswz)) << 4));
#pragma unroll
            for (int n = 0; n < 4; ++n) {
                const int col = (n << 4) + colL;
                const int s = ((col << 3) + (c ^ (col & 7))) << 4;
                short8 bh = *(const short8*)(hB + s);
                short8 bl = *(const short8*)(lB + s);
                acc[n] = __builtin_amdgcn_mfma_f32_16x16x32_bf16(a, bh, acc[n], 0, 0, 0);
                acc[n] = __builtin_amdgcn_mfma_f32_16x16x32_bf16(a, bl, acc[n], 0, 0, 0);
            }
        }
        __syncthreads();
    }

    // ---- epilogue: C/D layout col = lane&15, row = (lane>>4)*4 + reg (m89/m91)
    const int m32 = outmode ? flags[0] : 0;
    const int r0 = rowBase + (w << 4) + ((lane >> 4) << 2);
#pragma unroll
    for (int n = 0; n < 4; ++n) {
        const int col = colBase + (n << 4) + colL;
        const float bv = bias ? bias[col] : 0.0f;
#pragma unroll
        for (int r = 0; r < 4; ++r) {
            const int row = r0 + r;
            if (row < N) {
                float v = acc[n][r];
                if (dinv) v *= dinv[row];
                v += bv;
                size_t o = (size_t)row * F + col;
                if (m32) ((float*)out)[o] = v;
                else     ((bf16*)out)[o] = __float2bfloat16(v);
            }
        }
    }
}

// ---------------- fused gather-aggregate + self-loop + bias + act -----------
template <int F>
static __device__ __forceinline__ void acc_row(const bf16* __restrict__ Hs, int row, int lane,
                                               float* acc) {
    if constexpr (F == 64) {
        unsigned short u = ((const unsigned short*)Hs)[(size_t)row * 64 + lane];
        union { unsigned int i; float f; } c; c.i = (unsigned int)u << 16;
        acc[0] += c.f;
    } else if constexpr (F == 128) {
        unsigned int u = ((const unsigned int*)(Hs + (size_t)row * 128))[lane];
        union { unsigned int i; float f; } lo, hi;
        lo.i = u << 16; hi.i = u & 0xffff0000u;
        acc[0] += lo.f; acc[1] += hi.f;
    } else {
        uint2 u = ((const uint2*)(Hs + (size_t)row * 256))[lane];
        union { unsigned int i; float f; } a, b, c, d;
        a.i = u.x << 16; b.i = u.x & 0xffff0000u;
        c.i = u.y << 16; d.i = u.y & 0xffff0000u;
        acc[0] += a.f; acc[1] += b.f; acc[2] += c.f; acc[3] += d.f;
    }
}

template <int F>
__global__ void gather_kernel(const bf16* __restrict__ Hs, const int* __restrict__ rowPtr,
                              const int* __restrict__ sortedSrc, const float* __restrict__ dinv,
                              const float* __restrict__ bias, bf16* __restrict__ out,
                              int relu, int N) {
    constexpr int WPL = F / 64;                    // bf16 per lane
    int node = blockIdx.x * (blockDim.x >> 6) + (threadIdx.x >> 6);
    int lane = threadIdx.x & 63;
    if (node >= N) return;
    float acc[WPL];
#pragma unroll
    for (int w = 0; w < WPL; ++w) acc[w] = 0.0f;
    acc_row<F>(Hs, node, lane, acc);               // self-loop term
    const int beg = rowPtr[node], end = rowPtr[node + 1];
    for (int b = beg; b < end; b += 64) {
        int n = end - b; if (n > 64) n = 64;
        int myS = (lane < n) ? sortedSrc[b + lane] : 0;
        int j = 0;
        for (; j + 1 < n; j += 2) {               // 2 gathers in flight
            int s0 = __shfl(myS, j), s1 = __shfl(myS, j + 1);
            acc_row<F>(Hs, s0, lane, acc);
            acc_row<F>(Hs, s1, lane, acc);
        }
        if (j < n) acc_row<F>(Hs, __shfl(myS, j), lane, acc);
    }
    const float di = dinv[node];
    if constexpr (F == 64) {
        float v = acc[0] * di + bias[lane];
        if (relu) v = fmaxf(v, 0.0f);
        bf16 o = __float2bfloat16(v);
        ((unsigned short*)out)[(size_t)node * 64 + lane] = *(unsigned short*)&o;
    } else if constexpr (F == 128) {
        float v0 = acc[0] * di + bias[2 * lane];
        float v1 = acc[1] * di + bias[2 * lane + 1];
        if (relu) { v0 = fmaxf(v0, 0.0f); v1 = fmaxf(v1, 0.0f); }
        ((unsigned int*)(out + (size_t)node * 128))[lane] = packbf2(v0, v1);
    } else {
        float v0 = acc[0] * di + bias[4 * lane];
        float v1 = acc[1] * di + bias[4 * lane + 1];
        float v2 = acc[2] * di + bias[4 * lane + 2];
        float v3 = acc[3] * di + bias[4 * lane + 3];
        if (relu) { v0 = fmaxf(v0, 0.0f); v1 = fmaxf(v1, 0.0f);
                    v2 = fmaxf(v2, 0.0f); v3 = fmaxf(v3, 0.0f); }
        uint2 p; p.x = packbf2(v0, v1); p.y = packbf2(v2, v3);
        ((uint2*)(out + (size_t)node * 256))[lane] = p;
    }
}

// ---------------- link predictor --------------------------------------------
// Linear-before-sigmoid => per-node partials: a[n]=z[n]@lw[:64], b[n]=z[n]@lw[64:].
// edge_prob = sigmoid(a[src] + b[dst] + lb). ab[] is 400 KB -> L2-resident.
__global__ void link_pre(const bf16* __restrict__ Z, const float* __restrict__ lw,
                         float* __restrict__ ab, int N) {
    int node = blockIdx.x * (blockDim.x >> 6) + (threadIdx.x >> 6);
    int lane = threadIdx.x & 63;
    if (node >= N) return;
    float zv = b2f(Z[(size_t)node * 64 + lane]);
    float va = zv * lw[lane];
    float vb = zv * lw[64 + lane];
#pragma unroll
    for (int off = 32; off > 0; off >>= 1) {
        va += __shfl_down(va, off);
        vb += __shfl_down(vb, off);
    }
    if (lane == 0) { ab[2 * node] = va; ab[2 * node + 1] = vb; }
}

__global__ void link_edge(const float* __restrict__ ab, const int* __restrict__ srcv,
                          const int* __restrict__ dstv, const float* __restrict__ lb,
                          void* __restrict__ out, const int* __restrict__ flags,
                          size_t outOff, int E) {
    int e = blockIdx.x * blockDim.x + threadIdx.x;
    if (e >= E) return;
    float v = ab[2 * srcv[e]] + ab[2 * dstv[e] + 1] + lb[0];
    float sv = 1.0f / (1.0f + expf(-v));
    if (flags[0]) ((float*)out)[outOff + e] = sv;
    else          ((bf16*)out)[outOff + e] = __float2bfloat16(sv);
}

// ---------------- launch ----------------------------------------------------
extern "C" void kernel_launch(void* const* d_in, const int* in_sizes, int n_in,
                              void* d_out, int out_size, void* d_ws, size_t ws_size,
                              hipStream_t stream) {
    const int N = in_sizes[0] / 128;   // 50000
    const int E = in_sizes[1] / 2;     // 800000

    char* base = (char*)d_ws;
    size_t off = 0;
    auto alloc = [&](size_t bytes) { char* p = base + off; off = (off + bytes + 255) & ~(size_t)255; return p; };
    int*   flags  = (int*)  alloc(256);
    float* dinv   = (float*)alloc((size_t)N * 4);
    float* Wc     = (float*)alloc((size_t)210689 * 4);
    int*   counts = (int*)  alloc((size_t)N * 4);
    int*   rowPtr = (int*)  alloc(((size_t)N + 1) * 4);
    int*   cursor = (int*)  alloc((size_t)N * 4);
    int*   sortedSrc = (int*)alloc((size_t)E * 4);
    int*   srcd   = (int*)  alloc((size_t)E * 4);
    int*   dstd   = (int*)  alloc((size_t)E * 4);
    bf16*  Hs     = (bf16*) alloc((size_t)N * 256 * 2);  // scaled GEMM out H'
    bf16*  P0     = (bf16*) alloc((size_t)N * 256 * 2);  // layer output
    bf16*  z      = (bf16*) alloc((size_t)N * 64 * 2);
    bf16*  Wth    = (bf16*) alloc((size_t)208896 * 2);   // transposed bf16-hi weights
    bf16*  Wtl    = (bf16*) alloc((size_t)208896 * 2);   // transposed bf16-lo residuals
    float* ab     = (float*)alloc((size_t)N * 2 * 4);    // per-node link partials
    int*   blockSums = (int*)alloc(256 * 4);
    int*   blockOff  = (int*)alloc(256 * 4);

    // fp32 canon offsets (biases + link weights only now)
    const int W_EB1 = 16384, W_EB2 = 24704, W_EFB = 28864, W_DB1 = 45312,
              W_DB2 = 78336, W_DFB = 209536, W_LW = 210560, W_LB = 210688;
    // transposed hi/lo weight offsets (elements)
    const int T_EW1 = 0, T_EW2 = 16384, T_EFW = 24576, T_DW1 = 28672,
              T_DW2 = 45056, T_DFW = 77824;

    det_kernel<<<1, 256, 0, stream>>>((const unsigned short*)d_in[0], (const int*)d_in[1], flags);
    canon_edges<<<(E + 255) / 256, 256, 0, stream>>>((const int*)d_in[1], flags, srcd, dstd, E);

    // CSR + dinv (multi-block scan: N=50000 -> 196 blocks <= 256)
    hipMemsetAsync(counts, 0, (size_t)N * 4, stream);
    hist_kernel<<<(E + 255) / 256, 256, 0, stream>>>(dstd, counts, E);
    const int gScan = (N + 255) / 256;
    scan_part1<<<gScan, 256, 0, stream>>>(counts, blockSums, N);
    scan_part2<<<1, 256, 0, stream>>>(blockSums, blockOff, rowPtr + N, gScan);
    scan_part3<<<gScan, 256, 0, stream>>>(counts, blockOff, rowPtr, cursor, dinv, N);
    scatter_kernel<<<(E + 255) / 256, 256, 0, stream>>>(srcd, dstd, cursor, sortedSrc, E);

    {   // biases / link weights -> canonical fp32
        const int idx[8]  = {3, 5, 7, 9, 11, 13, 14, 15};
        const int woff[8] = {W_EB1, W_EB2, W_EFB, W_DB1, W_DB2, W_DFB, W_LW, W_LB};
        for (int j = 0; j < 8; ++j) {
            int n = in_sizes[idx[j]];
            canon_w<<<(n + 255) / 256, 256, 0, stream>>>(d_in[idx[j]], flags, Wc + woff[j], n);
        }
    }
    {   // GEMM weights -> transposed bf16 hi/lo split
        const int idx[6]  = {2, 4, 6, 8, 10, 12};
        const int toff[6] = {T_EW1, T_EW2, T_EFW, T_DW1, T_DW2, T_DFW};
        const int kk[6]   = {128, 128, 64, 64, 256, 128};
        const int ff[6]   = {128, 64, 64, 256, 128, 1024};
        for (int j = 0; j < 6; ++j) {
            int n = kk[j] * ff[j];
            prep_wt<<<(n + 255) / 256, 256, 0, stream>>>(d_in[idx[j]], flags,
                                                         Wth + toff[j], Wtl + toff[j], kk[j], ff[j]);
        }
    }
    canon_x<<<(N * 128 + 255) / 256, 256, 0, stream>>>(d_in[0], flags, P0, N * 128);

    const int gRB = (N + 63) / 64;     // 782 row blocks (tail block: 16 valid rows)
    const int gG = (N + 3) / 4;        // gather: 4 nodes (waves) per 256-block

    // Encoder GCN1: 128 -> 128 (H' = dinv * X@W), ReLU applied in gather
    mfma_gemm<128><<<dim3(2, gRB), 256, 0, stream>>>(P0, Wth + T_EW1, Wtl + T_EW1,
                                                     nullptr, dinv, Hs, flags, 0, 128, N);
    gather_kernel<128><<<gG, 256, 0, stream>>>(Hs, rowPtr, sortedSrc, dinv, Wc + W_EB1, P0, 1, N);

    // Encoder GCN2: 128 -> 64
    mfma_gemm<128><<<dim3(1, gRB), 256, 0, stream>>>(P0, Wth + T_EW2, Wtl + T_EW2,
                                                     nullptr, dinv, Hs, flags, 0, 64, N);
    gather_kernel<64><<<gG, 256, 0, stream>>>(Hs, rowPtr, sortedSrc, dinv, Wc + W_EB2, P0, 0, N);

    // Latent fc: z = P0 @ efw + efb
    mfma_gemm<64><<<dim3(1, gRB), 256, 0, stream>>>(P0, Wth + T_EFW, Wtl + T_EFW,
                                                    Wc + W_EFB, nullptr, z, flags, 0, 64, N);

    // link partials can go as soon as z exists (overlap with decoder GEMMs)
    link_pre<<<gG, 256, 0, stream>>>(z, Wc + W_LW, ab, N);

    // Decoder GCN1: 64 -> 256, ReLU in gather
    mfma_gemm<64><<<dim3(4, gRB), 256, 0, stream>>>(z, Wth + T_DW1, Wtl + T_DW1,
                                                    nullptr, dinv, Hs, flags, 0, 256, N);
    gather_kernel<256><<<gG, 256, 0, stream>>>(Hs, rowPtr, sortedSrc, dinv, Wc + W_DB1, P0, 1, N);

    // Decoder GCN2: 256 -> 128
    mfma_gemm<256><<<dim3(2, gRB), 256, 0, stream>>>(P0, Wth + T_DW2, Wtl + T_DW2,
                                                     nullptr, dinv, Hs, flags, 0, 128, N);
    gather_kernel<128><<<gG, 256, 0, stream>>>(Hs, rowPtr, sortedSrc, dinv, Wc + W_DB2, P0, 0, N);

    // x_hat = P0 @ dfw + dfb (128 -> 1024) into d_out, detected dtype
    mfma_gemm<128><<<dim3(16, gRB), 256, 0, stream>>>(P0, Wth + T_DFW, Wtl + T_DFW,
                                                      Wc + W_DFB, nullptr, d_out, flags, 1, 1024, N);

    // edge_probs: 1 thread/edge against L2-resident ab[]
    link_edge<<<(E + 255) / 256, 256, 0, stream>>>(ab, srcd, dstd, Wc + W_LB,
                                                   d_out, flags, (size_t)N * 1024, E);
}

// Round 4
// 621.307 us; speedup vs baseline: 1.9886x; 1.1102x over previous
//
#include <hip/hip_runtime.h>
#include <hip/hip_bf16.h>

using bf16 = __hip_bfloat16;
typedef __attribute__((ext_vector_type(8))) short short8;   // 8 bf16 = 4 VGPRs (MFMA A/B frag)
typedef __attribute__((ext_vector_type(4))) float f32x4;    // MFMA C/D frag

static __device__ __forceinline__ float b2f(bf16 x) { return __bfloat162float(x); }

static __device__ __forceinline__ unsigned int packbf2(float a, float b) {
    bf16 x = __float2bfloat16(a), y = __float2bfloat16(b);
    unsigned short ux = *(unsigned short*)&x, uy = *(unsigned short*)&y;
    return (unsigned int)ux | ((unsigned int)uy << 16);
}

// ---------------- dtype auto-detection (deterministic) -----------------------
// flags[0]=1 -> float inputs are fp32 (else bf16). flags[1]=1 -> edges int64.
__global__ void det_kernel(const unsigned short* __restrict__ xh,
                           const int* __restrict__ ei, int* __restrict__ flags) {
    __shared__ int s_exp, s_nz;
    if (threadIdx.x == 0) { s_exp = 0; s_nz = 0; }
    __syncthreads();
    if (threadIdx.x < 256) {
        unsigned short h = xh[threadIdx.x];
        int ef = (h >> 7) & 0xFF;
        if (ef < 100 || ef > 140) atomicAdd(&s_exp, 1);
    }
    for (int i = 1 + 2 * threadIdx.x; i < 4096; i += 2 * blockDim.x)
        if (ei[i] != 0) atomicAdd(&s_nz, 1);
    __syncthreads();
    if (threadIdx.x == 0) {
        flags[0] = (s_exp > 16) ? 1 : 0;
        flags[1] = (s_nz == 0) ? 1 : 0;
    }
}

// ---------------- canonicalizers --------------------------------------------
struct CanonWB { const void* src[8]; float* dst[8]; int n[8]; };

// one launch for all 8 small fp32 canon targets (biases + link weights)
__global__ void canon_w_batch(CanonWB cb, const int* __restrict__ flags) {
    int j = blockIdx.x;
    const void* src = cb.src[j];
    float* dst = cb.dst[j];
    int n = cb.n[j];
    int m32 = flags[0];
    for (int i = threadIdx.x; i < n; i += blockDim.x)
        dst[i] = m32 ? ((const float*)src)[i] : b2f(((const bf16*)src)[i]);
}

__global__ void canon_x(const void* __restrict__ src, const int* __restrict__ flags,
                        bf16* __restrict__ dst, int n) {
    int i = blockIdx.x * blockDim.x + threadIdx.x;
    if (i >= n) return;
    dst[i] = flags[0] ? __float2bfloat16(((const float*)src)[i]) : ((const bf16*)src)[i];
}

// canon_edges fused with degree histogram (counts must be pre-zeroed)
__global__ void canon_edges_hist(const int* __restrict__ ei, const int* __restrict__ flags,
                                 int* __restrict__ srcd, int* __restrict__ dstd,
                                 int* __restrict__ counts, int E) {
    int e = blockIdx.x * blockDim.x + threadIdx.x;
    if (e >= E) return;
    int s, d;
    if (flags[1]) { s = ei[2 * e]; d = ei[2 * E + 2 * e]; }
    else          { s = ei[e];     d = ei[E + e]; }
    srcd[e] = s; dstd[e] = d;
    atomicAdd(&counts[d], 1);
}

// Split fp32 weights W[K,F] into transposed bf16 hi/lo pair Wt[F,K].
// Batched: one launch covers all 6 GEMM weights. All K are pow2 -> shifts.
struct PrepB { const void* src[6]; int lgK[6]; int F[6]; int off[6]; int end[6]; };

__global__ void prep_wt_batch(PrepB pb, const int* __restrict__ flags,
                              bf16* __restrict__ Wth, bf16* __restrict__ Wtl, int total) {
    int g = blockIdx.x * blockDim.x + threadIdx.x;
    if (g >= total) return;
    int j = 0;
#pragma unroll
    for (int t = 0; t < 6; ++t) if (g >= pb.end[t]) j = t + 1;
    const void* src = pb.src[j];
    int lgK = pb.lgK[j], F = pb.F[j];
    int local = g - pb.off[j];
    int f = local >> lgK, k = local & ((1 << lgK) - 1);
    float v = flags[0] ? ((const float*)src)[((size_t)k << 0) * F + (size_t)k * (F - 1) ? 0 : 0] : 0.0f; // placeholder (rewritten below)
    // NOTE: expression above is dead; real load:
    v = flags[0] ? ((const float*)src)[(size_t)k * F + f]
                 : b2f(((const bf16*)src)[(size_t)k * F + f]);
    bf16 hi = __float2bfloat16(v);
    float lo = v - b2f(hi);
    Wth[g] = hi;
    Wtl[g] = __float2bfloat16(lo);
}

// ---------------- CSR build -------------------------------------------------
// Multi-block scan (196 blocks x 256 thr); monolithic 1-CU scan was 134 us.
__global__ void scan_part1(const int* __restrict__ counts, int* __restrict__ blockSums, int N) {
    __shared__ int red[256];
    int i = blockIdx.x * 256 + threadIdx.x;
    red[threadIdx.x] = (i < N) ? counts[i] : 0;
    __syncthreads();
    for (int off = 128; off > 0; off >>= 1) {
        if (threadIdx.x < off) red[threadIdx.x] += red[threadIdx.x + off];
        __syncthreads();
    }
    if (threadIdx.x == 0) blockSums[blockIdx.x] = red[0];
}

__global__ void scan_part2(const int* __restrict__ blockSums, int* __restrict__ blockOff,
                           int* __restrict__ rowPtrN, int G) {
    __shared__ int s[256];
    int t = threadIdx.x;
    s[t] = (t < G) ? blockSums[t] : 0;
    __syncthreads();
    for (int off = 1; off < 256; off <<= 1) {
        int v = (t >= off) ? s[t - off] : 0;
        __syncthreads();
        s[t] += v;
        __syncthreads();
    }
    if (t < G) blockOff[t] = (t > 0) ? s[t - 1] : 0;
    if (t == 255) *rowPtrN = s[255];
}

__global__ void scan_part3(const int* __restrict__ counts, const int* __restrict__ blockOff,
                           int* __restrict__ rowPtr, int* __restrict__ cursor,
                           float* __restrict__ dinv, int N) {
    __shared__ int s[256];
    int t = threadIdx.x;
    int i = blockIdx.x * 256 + t;
    int c = (i < N) ? counts[i] : 0;
    s[t] = c;
    __syncthreads();
    for (int off = 1; off < 256; off <<= 1) {
        int v = (t >= off) ? s[t - off] : 0;
        __syncthreads();
        s[t] += v;
        __syncthreads();
    }
    if (i < N) {
        int o = blockOff[blockIdx.x] + s[t] - c;     // exclusive prefix
        rowPtr[i] = o;
        cursor[i] = o;
        dinv[i] = rsqrtf((float)c + 1.0f);
    }
}

__global__ void scatter_kernel(const int* __restrict__ srcv, const int* __restrict__ dstv,
                               int* __restrict__ cursor, int* __restrict__ sortedSrc, int E) {
    int e = blockIdx.x * blockDim.x + threadIdx.x;
    if (e >= E) return;
    int p = atomicAdd(&cursor[dstv[e]], 1);
    sortedSrc[p] = srcv[e];
}

// ---------------- MFMA GEMM -------------------------------------------------
// C[N,F] = A[N,K](bf16) @ (Wth+Wtl)[K,F].
// Epilogue: v = acc*dinv_pre?[row] + bias?[col]; relu?; write out (bf16 or flag dtype);
//           optionally out2[row,col] = bf16(v * dinv2[row])  (latent z / zs pair).
// Block: 256 thr = 4 waves; tile 64x64; K chunked by 64. LDS XOR-swizzle per rule 21.
template <int K>
__global__ __launch_bounds__(256)
void mfma_gemm(const bf16* __restrict__ A,
               const bf16* __restrict__ Wth, const bf16* __restrict__ Wtl,
               const float* __restrict__ bias, const float* __restrict__ dinv,
               void* __restrict__ out, const int* __restrict__ flags,
               int outmode, int relu, bf16* __restrict__ out2,
               const float* __restrict__ dinv2, int F, int N) {
    __shared__ uint4 lds4[1536];               // 24 KB = 1536 x 16B granules
    char* lds = (char*)lds4;
    const int tid = threadIdx.x;
    const int w = tid >> 6, lane = tid & 63;
    const int rowBase = blockIdx.y * 64;
    const int colBase = blockIdx.x * 64;

    f32x4 zero = {0.f, 0.f, 0.f, 0.f};
    f32x4 acc[4];
#pragma unroll
    for (int n = 0; n < 4; ++n) acc[n] = zero;

    const int arow = (w << 4) + (lane & 15);
    const int aswz = arow & 7;
    const int colL = lane & 15;

    for (int kc = 0; kc < K; kc += 64) {
#pragma unroll
        for (int i = 0; i < 6; ++i) {
            const int g = i * 256 + tid;
            char* dst = lds + ((i * 256 + (w << 6)) << 4);
            const bf16* src;
            if (g < 512) {
                int r = g >> 3, c = g & 7;
                int gr = rowBase + r; if (gr >= N) gr = N - 1;
                src = A + (size_t)gr * K + kc + ((c ^ (r & 7)) << 3);
            } else if (g < 1024) {
                int h = g - 512; int cl = h >> 3, c = h & 7;
                src = Wth + (size_t)(colBase + cl) * K + kc + ((c ^ (cl & 7)) << 3);
            } else {
                int h = g - 1024; int cl = h >> 3, c = h & 7;
                src = Wtl + (size_t)(colBase + cl) * K + kc + ((c ^ (cl & 7)) << 3);
            }
            __builtin_amdgcn_global_load_lds(
                (const __attribute__((address_space(1))) void*)src,
                (__attribute__((address_space(3))) void*)dst, 16, 0, 0);
        }
        __syncthreads();

        const char* aB = lds;
        const char* hB = lds + 8192;
        const char* lB = lds + 16384;
#pragma unroll
        for (int ks = 0; ks < 2; ++ks) {
            const int c = (ks << 2) + (lane >> 4);
            short8 a = *(const short8*)(aB + (((arow << 3) + (c ^ aswz)) << 4));
#pragma unroll
            for (int n = 0; n < 4; ++n) {
                const int col = (n << 4) + colL;
                const int s = ((col << 3) + (c ^ (col & 7))) << 4;
                short8 bh = *(const short8*)(hB + s);
                short8 bl = *(const short8*)(lB + s);
                acc[n] = __builtin_amdgcn_mfma_f32_16x16x32_bf16(a, bh, acc[n], 0, 0, 0);
                acc[n] = __builtin_amdgcn_mfma_f32_16x16x32_bf16(a, bl, acc[n], 0, 0, 0);
            }
        }
        __syncthreads();
    }

    // C/D layout: col = lane&15, row = (lane>>4)*4 + reg (m89/m91)
    const int m32 = outmode ? flags[0] : 0;
    const int r0 = rowBase + (w << 4) + ((lane >> 4) << 2);
#pragma unroll
    for (int n = 0; n < 4; ++n) {
        const int col = colBase + (n << 4) + colL;
        const float bv = bias ? bias[col] : 0.0f;
#pragma unroll
        for (int r = 0; r < 4; ++r) {
            const int row = r0 + r;
            if (row < N) {
                float v = acc[n][r];
                if (dinv) v *= dinv[row];
                v += bv;
                if (relu) v = fmaxf(v, 0.0f);
                size_t o = (size_t)row * F + col;
                if (m32) ((float*)out)[o] = v;
                else     ((bf16*)out)[o] = __float2bfloat16(v);
                if (out2) out2[o] = __float2bfloat16(v * dinv2[row]);
            }
        }
    }
}

// ---------------- fused gather-aggregate + self-loop + bias + act -----------
template <int F>
static __device__ __forceinline__ void acc_row(const bf16* __restrict__ Hs, int row, int lane,
                                               float* acc) {
    if constexpr (F == 64) {
        unsigned short u = ((const unsigned short*)Hs)[(size_t)row * 64 + lane];
        union { unsigned int i; float f; } c; c.i = (unsigned int)u << 16;
        acc[0] += c.f;
    } else if constexpr (F == 128) {
        unsigned int u = ((const unsigned int*)(Hs + (size_t)row * 128))[lane];
        union { unsigned int i; float f; } lo, hi;
        lo.i = u << 16; hi.i = u & 0xffff0000u;
        acc[0] += lo.f; acc[1] += hi.f;
    } else {
        uint2 u = ((const uint2*)(Hs + (size_t)row * 256))[lane];
        union { unsigned int i; float f; } a, b, c, d;
        a.i = u.x << 16; b.i = u.x & 0xffff0000u;
        c.i = u.y << 16; d.i = u.y & 0xffff0000u;
        acc[0] += a.f; acc[1] += b.f; acc[2] += c.f; acc[3] += d.f;
    }
}

template <int F>
__global__ void gather_kernel(const bf16* __restrict__ Hs, const int* __restrict__ rowPtr,
                              const int* __restrict__ sortedSrc, const float* __restrict__ dinv,
                              const float* __restrict__ bias, bf16* __restrict__ out,
                              int relu, int N) {
    constexpr int WPL = F / 64;                    // fp32 acc words per lane
    int node = blockIdx.x * (blockDim.x >> 6) + (threadIdx.x >> 6);
    int lane = threadIdx.x & 63;
    if (node >= N) return;
    float acc[WPL];
#pragma unroll
    for (int w = 0; w < WPL; ++w) acc[w] = 0.0f;
    acc_row<F>(Hs, node, lane, acc);               // self-loop term
    const int beg = rowPtr[node], end = rowPtr[node + 1];
    for (int b = beg; b < end; b += 64) {
        int n = end - b; if (n > 64) n = 64;
        int myS = (lane < n) ? sortedSrc[b + lane] : 0;
        int j = 0;
        for (; j + 3 < n; j += 4) {               // 4 gathers in flight (latency-bound)
            int s0 = __shfl(myS, j),     s1 = __shfl(myS, j + 1);
            int s2 = __shfl(myS, j + 2), s3 = __shfl(myS, j + 3);
            acc_row<F>(Hs, s0, lane, acc);
            acc_row<F>(Hs, s1, lane, acc);
            acc_row<F>(Hs, s2, lane, acc);
            acc_row<F>(Hs, s3, lane, acc);
        }
        for (; j < n; ++j) acc_row<F>(Hs, __shfl(myS, j), lane, acc);
    }
    const float di = dinv[node];
    if constexpr (F == 64) {
        float v = acc[0] * di + (bias ? bias[lane] : 0.0f);
        if (relu) v = fmaxf(v, 0.0f);
        bf16 o = __float2bfloat16(v);
        ((unsigned short*)out)[(size_t)node * 64 + lane] = *(unsigned short*)&o;
    } else if constexpr (F == 128) {
        float b0 = bias ? bias[2 * lane] : 0.0f, b1 = bias ? bias[2 * lane + 1] : 0.0f;
        float v0 = acc[0] * di + b0;
        float v1 = acc[1] * di + b1;
        if (relu) { v0 = fmaxf(v0, 0.0f); v1 = fmaxf(v1, 0.0f); }
        ((unsigned int*)(out + (size_t)node * 128))[lane] = packbf2(v0, v1);
    } else {
        float v0 = acc[0] * di + (bias ? bias[4 * lane] : 0.0f);
        float v1 = acc[1] * di + (bias ? bias[4 * lane + 1] : 0.0f);
        float v2 = acc[2] * di + (bias ? bias[4 * lane + 2] : 0.0f);
        float v3 = acc[3] * di + (bias ? bias[4 * lane + 3] : 0.0f);
        if (relu) { v0 = fmaxf(v0, 0.0f); v1 = fmaxf(v1, 0.0f);
                    v2 = fmaxf(v2, 0.0f); v3 = fmaxf(v3, 0.0f); }
        uint2 p; p.x = packbf2(v0, v1); p.y = packbf2(v2, v3);
        ((uint2*)(out + (size_t)node * 256))[lane] = p;
    }
}

// ---------------- link predictor --------------------------------------------
__global__ void link_pre(const bf16* __restrict__ Z, const float* __restrict__ lw,
                         float* __restrict__ ab, int N) {
    int node = blockIdx.x * (blockDim.x >> 6) + (threadIdx.x >> 6);
    int lane = threadIdx.x & 63;
    if (node >= N) return;
    float zv = b2f(Z[(size_t)node * 64 + lane]);
    float va = zv * lw[lane];
    float vb = zv * lw[64 + lane];
#pragma unroll
    for (int off = 32; off > 0; off >>= 1) {
        va += __shfl_down(va, off);
        vb += __shfl_down(vb, off);
    }
    if (lane == 0) { ab[2 * node] = va; ab[2 * node + 1] = vb; }
}

__global__ void link_edge(const float* __restrict__ ab, const int* __restrict__ srcv,
                          const int* __restrict__ dstv, const float* __restrict__ lb,
                          void* __restrict__ out, const int* __restrict__ flags,
                          size_t outOff, int E) {
    int e = blockIdx.x * blockDim.x + threadIdx.x;
    if (e >= E) return;
    float v = ab[2 * srcv[e]] + ab[2 * dstv[e] + 1] + lb[0];
    float sv = 1.0f / (1.0f + expf(-v));
    if (flags[0]) ((float*)out)[outOff + e] = sv;
    else          ((bf16*)out)[outOff + e] = __float2bfloat16(sv);
}

// ---------------- launch ----------------------------------------------------
extern "C" void kernel_launch(void* const* d_in, const int* in_sizes, int n_in,
                              void* d_out, int out_size, void* d_ws, size_t ws_size,
                              hipStream_t stream) {
    const int N = in_sizes[0] / 128;   // 50000
    const int E = in_sizes[1] / 2;     // 800000

    char* base = (char*)d_ws;
    size_t off = 0;
    auto alloc = [&](size_t bytes) { char* p = base + off; off = (off + bytes + 255) & ~(size_t)255; return p; };
    int*   flags  = (int*)  alloc(256);
    float* dinv   = (float*)alloc((size_t)N * 4);
    float* Wc     = (float*)alloc((size_t)210689 * 4);
    int*   counts = (int*)  alloc((size_t)N * 4);
    int*   rowPtr = (int*)  alloc(((size_t)N + 1) * 4);
    int*   cursor = (int*)  alloc((size_t)N * 4);
    int*   sortedSrc = (int*)alloc((size_t)E * 4);
    int*   srcd   = (int*)  alloc((size_t)E * 4);
    int*   dstd   = (int*)  alloc((size_t)E * 4);
    bf16*  Hs     = (bf16*) alloc((size_t)N * 256 * 2);  // scaled GEMM out / agg buffer
    bf16*  P0     = (bf16*) alloc((size_t)N * 256 * 2);  // layer output
    bf16*  z      = (bf16*) alloc((size_t)N * 64 * 2);
    bf16*  zs     = (bf16*) alloc((size_t)N * 64 * 2);   // dinv ⊙ z (decoder pre-gather input)
    bf16*  Wth    = (bf16*) alloc((size_t)208896 * 2);
    bf16*  Wtl    = (bf16*) alloc((size_t)208896 * 2);
    float* ab     = (float*)alloc((size_t)N * 2 * 4);
    int*   blockSums = (int*)alloc(256 * 4);
    int*   blockOff  = (int*)alloc(256 * 4);

    const int W_EB1 = 16384, W_EB2 = 24704, W_EFB = 28864, W_DB1 = 45312,
              W_DB2 = 78336, W_DFB = 209536, W_LW = 210560, W_LB = 210688;
    const int T_EW1 = 0, T_EW2 = 16384, T_EFW = 24576, T_DW1 = 28672,
              T_DW2 = 45056, T_DFW = 77824;

    det_kernel<<<1, 256, 0, stream>>>((const unsigned short*)d_in[0], (const int*)d_in[1], flags);

    // CSR + dinv (hist fused into edge canon; multi-block scan)
    hipMemsetAsync(counts, 0, (size_t)N * 4, stream);
    canon_edges_hist<<<(E + 255) / 256, 256, 0, stream>>>((const int*)d_in[1], flags,
                                                          srcd, dstd, counts, E);
    const int gScan = (N + 255) / 256;
    scan_part1<<<gScan, 256, 0, stream>>>(counts, blockSums, N);
    scan_part2<<<1, 256, 0, stream>>>(blockSums, blockOff, rowPtr + N, gScan);
    scan_part3<<<gScan, 256, 0, stream>>>(counts, blockOff, rowPtr, cursor, dinv, N);
    scatter_kernel<<<(E + 255) / 256, 256, 0, stream>>>(srcd, dstd, cursor, sortedSrc, E);

    {   // biases / link weights -> canonical fp32 (1 launch)
        CanonWB cb;
        const int idx[8]  = {3, 5, 7, 9, 11, 13, 14, 15};
        const int woff[8] = {W_EB1, W_EB2, W_EFB, W_DB1, W_DB2, W_DFB, W_LW, W_LB};
        for (int j = 0; j < 8; ++j) {
            cb.src[j] = d_in[idx[j]];
            cb.dst[j] = Wc + woff[j];
            cb.n[j] = in_sizes[idx[j]];
        }
        canon_w_batch<<<8, 256, 0, stream>>>(cb, flags);
    }
    {   // GEMM weights -> transposed bf16 hi/lo split (1 launch)
        PrepB pb;
        const int idx[6]  = {2, 4, 6, 8, 10, 12};
        const int toff[6] = {T_EW1, T_EW2, T_EFW, T_DW1, T_DW2, T_DFW};
        const int lgk[6]  = {7, 7, 6, 6, 8, 7};
        const int ff[6]   = {128, 64, 64, 256, 128, 1024};
        int total = 0;
        for (int j = 0; j < 6; ++j) {
            pb.src[j] = d_in[idx[j]];
            pb.lgK[j] = lgk[j];
            pb.F[j] = ff[j];
            pb.off[j] = toff[j];
            pb.end[j] = toff[j] + (ff[j] << lgk[j]);
            total = pb.end[j];
        }
        prep_wt_batch<<<(total + 255) / 256, 256, 0, stream>>>(pb, flags, Wth, Wtl, total);
    }
    canon_x<<<(N * 128 + 255) / 256, 256, 0, stream>>>(d_in[0], flags, P0, N * 128);

    const int gRB = (N + 63) / 64;
    const int gG = (N + 3) / 4;

    // Encoder GCN1: 128 -> 128 (H' = dinv * X@W), ReLU in gather
    mfma_gemm<128><<<dim3(2, gRB), 256, 0, stream>>>(P0, Wth + T_EW1, Wtl + T_EW1,
                                                     nullptr, dinv, Hs, flags, 0, 0,
                                                     nullptr, nullptr, 128, N);
    gather_kernel<128><<<gG, 256, 0, stream>>>(Hs, rowPtr, sortedSrc, dinv, Wc + W_EB1, P0, 1, N);

    // Encoder GCN2: 128 -> 64
    mfma_gemm<128><<<dim3(1, gRB), 256, 0, stream>>>(P0, Wth + T_EW2, Wtl + T_EW2,
                                                     nullptr, dinv, Hs, flags, 0, 0,
                                                     nullptr, nullptr, 64, N);
    gather_kernel<64><<<gG, 256, 0, stream>>>(Hs, rowPtr, sortedSrc, dinv, Wc + W_EB2, P0, 0, N);

    // Latent fc: z = P0 @ efw + efb; zs = dinv ⊙ z (free in epilogue)
    mfma_gemm<64><<<dim3(1, gRB), 256, 0, stream>>>(P0, Wth + T_EFW, Wtl + T_EFW,
                                                    Wc + W_EFB, nullptr, z, flags, 0, 0,
                                                    zs, dinv, 64, N);

    // link partials (needs z only)
    link_pre<<<gG, 256, 0, stream>>>(z, Wc + W_LW, ab, N);

    // Decoder GCN1 (aggregate-before-transform): agg = dinv*(Σ zs + zs_self) on F=64,
    // then GEMM 64->256 with bias+ReLU. agg@W == agg(z@W) by linearity — 4x less gather traffic.
    gather_kernel<64><<<gG, 256, 0, stream>>>(zs, rowPtr, sortedSrc, dinv, nullptr, Hs, 0, N);
    mfma_gemm<64><<<dim3(4, gRB), 256, 0, stream>>>(Hs, Wth + T_DW1, Wtl + T_DW1,
                                                    Wc + W_DB1, nullptr, P0, flags, 0, 1,
                                                    nullptr, nullptr, 256, N);

    // Decoder GCN2: 256 -> 128 (transform-then-aggregate: min(256,128)=128)
    mfma_gemm<256><<<dim3(2, gRB), 256, 0, stream>>>(P0, Wth + T_DW2, Wtl + T_DW2,
                                                     nullptr, dinv, Hs, flags, 0, 0,
                                                     nullptr, nullptr, 128, N);
    gather_kernel<128><<<gG, 256, 0, stream>>>(Hs, rowPtr, sortedSrc, dinv, Wc + W_DB2, P0, 0, N);

    // x_hat = P0 @ dfw + dfb (128 -> 1024) into d_out, detected dtype
    mfma_gemm<128><<<dim3(16, gRB), 256, 0, stream>>>(P0, Wth + T_DFW, Wtl + T_DFW,
                                                      Wc + W_DFB, nullptr, d_out, flags, 1, 0,
                                                      nullptr, nullptr, 1024, N);

    // edge_probs
    link_edge<<<(E + 255) / 256, 256, 0, stream>>>(ab, srcd, dstd, Wc + W_LB,
                                                   d_out, flags, (size_t)N * 1024, E);
}